// Round 10
// baseline (1031.420 us; speedup 1.0000x reference)
//
#include <hip/hip_runtime.h>

#define EPS 1e-5f
typedef unsigned short u16;
typedef unsigned int u32;

typedef __attribute__((ext_vector_type(8))) short bf16x8;
typedef __attribute__((ext_vector_type(4))) float f32x4;

// ---------- bf16 helpers ----------
__device__ __forceinline__ float bf2f(u16 h) {
    u32 u = ((u32)h) << 16;
    return __builtin_bit_cast(float, u);
}
__device__ __forceinline__ u16 f2bf(float f) {
    u32 u = __builtin_bit_cast(u32, f);
    u32 r = (u + 0x7fffu + ((u >> 16) & 1u)) >> 16;   // RNE
    return (u16)r;
}
__device__ __forceinline__ u32 pack2(float a, float b) {
    return (u32)f2bf(a) | ((u32)f2bf(b) << 16);
}

// ============================================================
// K1: qkv[n,o,l] = sum_c W[o,c] * x[b,c,h,l]   (n = b*64+h)
// ============================================================
__global__ __launch_bounds__(256) void k1_gemm_qkv(
    const float* __restrict__ x, const float* __restrict__ Wq,
    float* __restrict__ qkv, float* __restrict__ stats)
{
    __shared__ float Wt[64 * 68];
    __shared__ float xt[64 * 128];
    const int tid = threadIdx.x;
    const int ot = blockIdx.x;
    const int n  = blockIdx.y;
    const int b = n >> 6, h = n & 63;
    const int to = tid >> 5, tl = tid & 31;
    const int o0 = to * 8, l0 = tl * 4;

    float acc[8][4];
#pragma unroll
    for (int r = 0; r < 8; ++r) { acc[r][0]=0.f; acc[r][1]=0.f; acc[r][2]=0.f; acc[r][3]=0.f; }

    for (int cb = 0; cb < 128; cb += 64) {
        __syncthreads();
#pragma unroll
        for (int k = 0; k < 4; ++k) {
            int f = tid + k * 256;
            int oo = f >> 4, c4 = f & 15;
            float4 v = *(const float4*)(Wq + (ot * 64 + oo) * 128 + cb + c4 * 4);
            *(float4*)(Wt + oo * 68 + c4 * 4) = v;
        }
#pragma unroll
        for (int k = 0; k < 8; ++k) {
            int f = tid + k * 256;
            int c = f >> 5, l4 = f & 31;
            float4 v = *(const float4*)(x + ((size_t)((b * 128 + cb + c) * 64 + h)) * 128 + l4 * 4);
            *(float4*)(xt + c * 128 + l4 * 4) = v;
        }
        __syncthreads();
#pragma unroll 4
        for (int c = 0; c < 64; ++c) {
            float4 xv = *(const float4*)(xt + c * 128 + l0);
#pragma unroll
            for (int r = 0; r < 8; ++r) {
                float w = Wt[(o0 + r) * 68 + c];
                acc[r][0] += w * xv.x; acc[r][1] += w * xv.y;
                acc[r][2] += w * xv.z; acc[r][3] += w * xv.w;
            }
        }
    }

#pragma unroll
    for (int r = 0; r < 8; ++r) {
        int o = ot * 64 + o0 + r;
        *(float4*)(qkv + ((size_t)n * 256 + o) * 128 + l0) =
            make_float4(acc[r][0], acc[r][1], acc[r][2], acc[r][3]);
        float s  = acc[r][0] + acc[r][1] + acc[r][2] + acc[r][3];
        float sq = acc[r][0]*acc[r][0] + acc[r][1]*acc[r][1] + acc[r][2]*acc[r][2] + acc[r][3]*acc[r][3];
#pragma unroll
        for (int m = 1; m < 32; m <<= 1) {
            s  += __shfl_xor(s, m);
            sq += __shfl_xor(sq, m);
        }
        if (tl == 0) {
            atomicAdd(&stats[o], s);
            atomicAdd(&stats[256 + o], sq);
        }
    }
}

__global__ void k3_coef_qkv(const float* __restrict__ stats,
                            const float* __restrict__ gamma, const float* __restrict__ beta,
                            float* __restrict__ coef)
{
    int o = threadIdx.x;
    const float cnt = 16384.f;
    float mean = stats[o] / cnt;
    float var  = stats[256 + o] / cnt - mean * mean;
    float a = gamma[o] * rsqrtf(var + EPS);
    coef[o] = a;
    coef[256 + o] = beta[o] - a * mean;
}

// ============================================================
// K4 v3 (pass 1): unchanged (512 thr, MFMA).
// ============================================================
__global__ __launch_bounds__(512, 4) void k4_pass1(
    const float* __restrict__ qkv, const float* __restrict__ rel,
    const float* __restrict__ cq, u16* __restrict__ qk,
    float* __restrict__ stats)
{
    __shared__ u16 QEb[128 * 136];
    __shared__ u16 KEb[128 * 136];
    __shared__ float red[8 * 6];
    const int tid = threadIdx.x;
    const int n = blockIdx.x >> 4, g = blockIdx.x & 15;

    const int pt = tid & 31, pi = tid >> 5;
    const int t0 = pt * 4, i0 = pi * 8;
    const int d0 = t0 - i0 + 120;

    float qes = 0.f, qesq = 0.f, kes = 0.f, kesq = 0.f;

#pragma unroll
    for (int mat = 0; mat < 2; ++mat) {
        float qv[4][4];
#pragma unroll
        for (int c = 0; c < 4; ++c) {
            int o = g * 16 + mat * 4 + c;
            float a = cq[o], bb = cq[256 + o];
            float4 x0 = *(const float4*)(qkv + ((size_t)n * 256 + o) * 128 + t0);
            qv[c][0] = fmaf(a, x0.x, bb); qv[c][1] = fmaf(a, x0.y, bb);
            qv[c][2] = fmaf(a, x0.z, bb); qv[c][3] = fmaf(a, x0.w, bb);
        }
        float rr[4][12];
#pragma unroll
        for (int c = 0; c < 4; ++c) {
            const float* p = rel + (mat * 4 + c) * 255 + d0;
#pragma unroll
            for (int j = 0; j < 3; ++j) {
                float4 v = *(const float4*)(p + j * 4);
                rr[c][j*4+0] = v.x; rr[c][j*4+1] = v.y;
                rr[c][j*4+2] = v.z; rr[c][j*4+3] = v.w;
            }
        }
        u16* MB = mat ? KEb : QEb;
        float s = 0.f, sq = 0.f;
#pragma unroll
        for (int ii = 0; ii < 8; ++ii) {
            float vv[4];
#pragma unroll
            for (int tt = 0; tt < 4; ++tt) {
                int dl = tt - ii + 7;
                float v = qv[0][tt] * rr[0][dl] + qv[1][tt] * rr[1][dl]
                        + qv[2][tt] * rr[2][dl] + qv[3][tt] * rr[3][dl];
                vv[tt] = v;
                s += v; sq = fmaf(v, v, sq);
            }
            *(uint2*)(MB + (i0 + ii) * 136 + t0) =
                make_uint2(pack2(vv[0], vv[1]), pack2(vv[2], vv[3]));
        }
        if (mat == 0) { qes = s; qesq = sq; } else { kes = s; kesq = sq; }
    }
    __syncthreads();

    const int lane = tid & 63, wv = tid >> 6;
    const int fm = lane & 15, fq = lane >> 4;

    f32x4 acc[8];
#pragma unroll
    for (int tj = 0; tj < 8; ++tj) acc[tj] = (f32x4){0.f, 0.f, 0.f, 0.f};

#pragma unroll
    for (int kb = 0; kb < 4; ++kb) {
        const int ko = kb * 32 + fq * 8;
        bf16x8 a0 = *(const bf16x8*)(QEb + (wv * 16 + fm) * 136 + ko);
#pragma unroll
        for (int tj = 0; tj < 8; ++tj) {
            bf16x8 bfr = *(const bf16x8*)(KEb + (tj * 16 + fm) * 136 + ko);
            acc[tj] = __builtin_amdgcn_mfma_f32_16x16x32_bf16(a0, bfr, acc[tj], 0, 0, 0);
        }
    }

    float qks = 0.f, qksq = 0.f;
#pragma unroll
    for (int tj = 0; tj < 8; ++tj) {
#pragma unroll
        for (int r = 0; r < 4; ++r) {
            float v = acc[tj][r];
            qks += v; qksq = fmaf(v, v, qksq);
            QEb[(wv * 16 + fq * 4 + r) * 136 + tj * 16 + fm] = f2bf(v);
        }
    }

#pragma unroll
    for (int m = 1; m < 64; m <<= 1) {
        qes += __shfl_xor(qes, m);  qesq += __shfl_xor(qesq, m);
        kes += __shfl_xor(kes, m);  kesq += __shfl_xor(kesq, m);
        qks += __shfl_xor(qks, m);  qksq += __shfl_xor(qksq, m);
    }
    if (lane == 0) {
        red[wv * 6 + 0] = qes; red[wv * 6 + 1] = qesq;
        red[wv * 6 + 2] = kes; red[wv * 6 + 3] = kesq;
        red[wv * 6 + 4] = qks; red[wv * 6 + 5] = qksq;
    }
    __syncthreads();

    u16* qkg = qk + (size_t)(n * 16 + g) * 16384;
#pragma unroll
    for (int k = 0; k < 4; ++k) {
        int f = tid + k * 512;
        int row = f >> 4, c8 = f & 15;
        uint4 v = *(const uint4*)(QEb + row * 136 + c8 * 8);
        *(uint4*)(qkg + row * 128 + c8 * 8) = v;
    }

    if (tid < 6) {
        float tot = 0.f;
#pragma unroll
        for (int w = 0; w < 8; ++w) tot += red[w * 6 + tid];
        int off = (tid & 1) ? 560 : 512;
        int ch = (tid < 2) ? (16 + g) : (tid < 4) ? (32 + g) : g;
        atomicAdd(&stats[off + ch], tot);
    }
}

__global__ void k5_coef_sim(const float* __restrict__ stats,
                            const float* __restrict__ gamma, const float* __restrict__ beta,
                            float* __restrict__ coef)
{
    int ch = threadIdx.x;
    if (ch < 48) {
        const float cnt = 2097152.f;
        float mean = stats[512 + ch] / cnt;
        float var  = stats[560 + ch] / cnt - mean * mean;
        float a = gamma[ch] * rsqrtf(var + EPS);
        coef[ch] = a;
        coef[48 + ch] = beta[ch] - a * mean;
    }
}

// ============================================================
// K6 v7 (pass 2): R5/R9's non-spilling inner loop, j-SPLIT ACROSS WAVES.
//  Wall time of v6 = single-wave serial time (one generation of waves,
//  16/CU): 128 latency-chained iterations. v7: 256 thr, i = tid&127,
//  h = tid>>7; each lane does j in [64h, 64h+64) -> HALF the serial
//  chain, and 2x resident waves (8 blocks/CU x 4 waves = 32/CU if
//  VGPR <= 64; R5/R9 measured 52). Cross-wave merge of (l, am, ame)
//  through LDS (relb reused after barrier, stride-17 floats = 2-way
//  bank aliasing = free). h=0 waves run the R9 epilogue verbatim.
// ============================================================
__global__ __launch_bounds__(256, 4) void k6_pass2(
    const float* __restrict__ qkv, const float* __restrict__ rel,
    const float* __restrict__ cq, const float* __restrict__ cs,
    const u16* __restrict__ qk,
    float* __restrict__ outraw, float* __restrict__ ostats)
{
    __shared__ u16 relb[256 * 24];     // [d][ch], d<255; reused as merge buf
    __shared__ u16 vb[128 * 8];        // [j][c]
    __shared__ float qn_s[8 * 128];    // q rows 0..3, k rows 4..7 (normalized)
    const int tid = threadIdx.x;
    const int n = blockIdx.x >> 4, g = blockIdx.x & 15;
    const int i = tid & 127, h = tid >> 7;

    // stage relb: 16 ch x 255 d
#pragma unroll
    for (int k = 0; k < 16; ++k) {
        int f = tid + k * 256;          // < 4096
        int c = f >> 8, d = f & 255;
        if (d < 255) relb[d * 24 + c] = f2bf(rel[c * 255 + d]);
    }
    // stage qn_s (q,k normalized fp32)
#pragma unroll
    for (int k = 0; k < 4; ++k) {
        int f = tid + k * 256;          // < 1024
        int c = f >> 7, t = f & 127;
        int o = g * 16 + c;
        qn_s[f] = fmaf(cq[o], qkv[((size_t)n * 256 + o) * 128 + t], cq[256 + o]);
    }
    // stage vb (v normalized bf16)
#pragma unroll
    for (int k = 0; k < 4; ++k) {
        int f = tid + k * 256;          // < 1024
        int c = f >> 7, j = f & 127;
        int o = g * 16 + 8 + c;
        float v = fmaf(cq[o], qkv[((size_t)n * 256 + o) * 128 + j], cq[256 + o]);
        vb[j * 8 + c] = f2bf(v);
    }
    __syncthreads();

    const float aqk = cs[g], aqe = cs[16 + g], ake = cs[32 + g];
    const float bsum = cs[48 + g] + cs[64 + g] + cs[80 + g];

    float q0 = qn_s[i],       q1 = qn_s[128 + i], q2 = qn_s[256 + i], q3 = qn_s[384 + i];
    float k0 = qn_s[512 + i], k1 = qn_s[640 + i], k2 = qn_s[768 + i], k3 = qn_s[896 + i];

    const u16* qkrow = qk + (size_t)(n * 16 + g) * 16384 + i * 128 + h * 64;

    float l = 0.f;
    float am[8], ame[8];
#pragma unroll
    for (int c = 0; c < 8; ++c) { am[c] = 0.f; ame[c] = 0.f; }

#pragma unroll
    for (int jc = 0; jc < 4; ++jc) {
        // qk chunk (16 bf16, per-lane contiguous, 16B aligned)
        union { uint4 v[2]; u16 hh[16]; } qh;
        qh.v[0] = *(const uint4*)(qkrow + jc * 16);
        qh.v[1] = *(const uint4*)(qkrow + jc * 16 + 8);

        const int jb = h * 64 + jc * 16;
        const int dbase = i + 127 - jb;
#pragma unroll
        for (int jl = 0; jl < 16; ++jl) {
            const int d = dbase - jl;
            bf16x8 rb = *(const bf16x8*)(relb + d * 24);
            bf16x8 rv = *(const bf16x8*)(relb + d * 24 + 8);
            bf16x8 vv = *(const bf16x8*)(vb + (jb + jl) * 8);
            float qe = q0 * bf2f((u16)rb[0]) + q1 * bf2f((u16)rb[1])
                     + q2 * bf2f((u16)rb[2]) + q3 * bf2f((u16)rb[3]);
            float ke = k0 * bf2f((u16)rb[4]) + k1 * bf2f((u16)rb[5])
                     + k2 * bf2f((u16)rb[6]) + k3 * bf2f((u16)rb[7]);
            float s = aqk * bf2f(qh.hh[jl]) + aqe * qe + ake * ke + bsum;
            float e = __expf(s);
            l += e;
#pragma unroll
            for (int c = 0; c < 8; ++c) {
                am[c]  = fmaf(e, bf2f((u16)vv[c]), am[c]);
                ame[c] = fmaf(e, bf2f((u16)rv[c]), ame[c]);
            }
        }
    }

    // ------- cross-wave merge: h=1 partials -> LDS, h=0 combines -------
    __syncthreads();                    // everyone done reading relb
    float* mrg = (float*)relb;          // 128 rows x 17 floats (8.7 KB)
    if (h) {
#pragma unroll
        for (int c = 0; c < 8; ++c) { mrg[i * 17 + c] = am[c]; mrg[i * 17 + 8 + c] = ame[c]; }
        mrg[i * 17 + 16] = l;
    }
    __syncthreads();
    if (h == 0) {
#pragma unroll
        for (int c = 0; c < 8; ++c) { am[c] += mrg[i * 17 + c]; ame[c] += mrg[i * 17 + 8 + c]; }
        l += mrg[i * 17 + 16];

        // epilogue: normalize, write out, BN stats (R9 shape, unchanged)
        float inv = 1.f / l;
        float o16[16];
#pragma unroll
        for (int c = 0; c < 8; ++c) { o16[2 * c] = am[c] * inv; o16[2 * c + 1] = ame[c] * inv; }

        float* orow = outraw + ((size_t)n * 256 + g * 16) * 128 + i;
#pragma unroll
        for (int c16 = 0; c16 < 16; ++c16) orow[c16 * 128] = o16[c16];

        const int lane = tid & 63;
#pragma unroll
        for (int c16 = 0; c16 < 16; ++c16) {
            float sv = o16[c16], sq = o16[c16] * o16[c16];
#pragma unroll
            for (int mm = 1; mm < 64; mm <<= 1) { sv += __shfl_xor(sv, mm); sq += __shfl_xor(sq, mm); }
            if (lane == 0) {
                atomicAdd(&ostats[g * 16 + c16], sv);
                atomicAdd(&ostats[256 + g * 16 + c16], sq);
            }
        }
    }
}

__global__ void k7_coef_out(const float* __restrict__ stats,
                            const float* __restrict__ gamma, const float* __restrict__ beta,
                            float* __restrict__ coef)
{
    int o = threadIdx.x;
    const float cnt = 16384.f;
    float mean = stats[608 + o] / cnt;
    float var  = stats[864 + o] / cnt - mean * mean;
    float a = gamma[o] * rsqrtf(var + EPS);
    coef[o] = a;
    coef[256 + o] = beta[o] - a * mean;
}

__global__ __launch_bounds__(256) void k8_final(
    const float* __restrict__ outraw, const float* __restrict__ co,
    float* __restrict__ out)
{
    int idx = blockIdx.x * 256 + threadIdx.x;
    int w  = idx & 127;
    int h  = (idx >> 7) & 63;
    int oc = (idx >> 13) & 127;
    int b  = idx >> 20;
    int n  = b * 64 + h;
    int o0 = oc * 2;
    float x0 = outraw[((size_t)n * 256 + o0) * 128 + w];
    float x1 = outraw[((size_t)n * 256 + o0 + 1) * 128 + w];
    out[idx] = (co[o0] * x0 + co[256 + o0]) + (co[o0 + 1] * x1 + co[256 + o0 + 1]);
}

// ============================================================
// Workspace layout (floats): unchanged from round 0.
// ============================================================
extern "C" void kernel_launch(void* const* d_in, const int* in_sizes, int n_in,
                              void* d_out, int out_size, void* d_ws, size_t ws_size,
                              hipStream_t stream)
{
    const float* x   = (const float*)d_in[0];
    const float* Wq  = (const float*)d_in[1];
    const float* gq  = (const float*)d_in[2];
    const float* bq  = (const float*)d_in[3];
    const float* rel = (const float*)d_in[4];
    const float* gs  = (const float*)d_in[5];
    const float* bs  = (const float*)d_in[6];
    const float* go  = (const float*)d_in[7];
    const float* bo  = (const float*)d_in[8];

    float* ws     = (float*)d_ws;
    float* qkv    = ws;
    float* outraw = ws + 4194304;
    u16*   qk     = (u16*)(ws + 8388608);
    float* stats  = ws + 25165824;
    float* cq     = stats + 1120;
    float* cs     = stats + 1632;
    float* co     = stats + 1728;

    (void)hipMemsetAsync(stats, 0, 1120 * sizeof(float), stream);

    k1_gemm_qkv<<<dim3(4, 128), 256, 0, stream>>>(x, Wq, qkv, stats);
    k3_coef_qkv<<<1, 256, 0, stream>>>(stats, gq, bq, cq);
    k4_pass1<<<2048, 512, 0, stream>>>(qkv, rel, cq, qk, stats);
    k5_coef_sim<<<1, 64, 0, stream>>>(stats, gs, bs, cs);
    k6_pass2<<<2048, 256, 0, stream>>>(qkv, rel, cq, cs, qk, outraw, stats + 608);
    k7_coef_out<<<1, 256, 0, stream>>>(stats, go, bo, co);
    k8_final<<<8192, 256, 0, stream>>>(outraw, co, (float*)d_out);
}

// Round 11
// 333.464 us; speedup vs baseline: 3.0930x; 3.0930x over previous
//
#include <hip/hip_runtime.h>

#define EPS 1e-5f
typedef unsigned short u16;
typedef unsigned int u32;

typedef __attribute__((ext_vector_type(8))) short bf16x8;
typedef __attribute__((ext_vector_type(4))) float f32x4;

// ---------- bf16 helpers ----------
__device__ __forceinline__ float bf2f(u16 h) {
    u32 u = ((u32)h) << 16;
    return __builtin_bit_cast(float, u);
}
__device__ __forceinline__ u16 f2bf(float f) {
    u32 u = __builtin_bit_cast(u32, f);
    u32 r = (u + 0x7fffu + ((u >> 16) & 1u)) >> 16;   // RNE
    return (u16)r;
}
__device__ __forceinline__ u32 pack2(float a, float b) {
    return (u32)f2bf(a) | ((u32)f2bf(b) << 16);
}

// ============================================================
// K1: qkv[n,o,l] = sum_c W[o,c] * x[b,c,h,l]   (n = b*64+h)
// ============================================================
__global__ __launch_bounds__(256) void k1_gemm_qkv(
    const float* __restrict__ x, const float* __restrict__ Wq,
    float* __restrict__ qkv, float* __restrict__ stats)
{
    __shared__ float Wt[64 * 68];
    __shared__ float xt[64 * 128];
    const int tid = threadIdx.x;
    const int ot = blockIdx.x;
    const int n  = blockIdx.y;
    const int b = n >> 6, h = n & 63;
    const int to = tid >> 5, tl = tid & 31;
    const int o0 = to * 8, l0 = tl * 4;

    float acc[8][4];
#pragma unroll
    for (int r = 0; r < 8; ++r) { acc[r][0]=0.f; acc[r][1]=0.f; acc[r][2]=0.f; acc[r][3]=0.f; }

    for (int cb = 0; cb < 128; cb += 64) {
        __syncthreads();
#pragma unroll
        for (int k = 0; k < 4; ++k) {
            int f = tid + k * 256;
            int oo = f >> 4, c4 = f & 15;
            float4 v = *(const float4*)(Wq + (ot * 64 + oo) * 128 + cb + c4 * 4);
            *(float4*)(Wt + oo * 68 + c4 * 4) = v;
        }
#pragma unroll
        for (int k = 0; k < 8; ++k) {
            int f = tid + k * 256;
            int c = f >> 5, l4 = f & 31;
            float4 v = *(const float4*)(x + ((size_t)((b * 128 + cb + c) * 64 + h)) * 128 + l4 * 4);
            *(float4*)(xt + c * 128 + l4 * 4) = v;
        }
        __syncthreads();
#pragma unroll 4
        for (int c = 0; c < 64; ++c) {
            float4 xv = *(const float4*)(xt + c * 128 + l0);
#pragma unroll
            for (int r = 0; r < 8; ++r) {
                float w = Wt[(o0 + r) * 68 + c];
                acc[r][0] += w * xv.x; acc[r][1] += w * xv.y;
                acc[r][2] += w * xv.z; acc[r][3] += w * xv.w;
            }
        }
    }

#pragma unroll
    for (int r = 0; r < 8; ++r) {
        int o = ot * 64 + o0 + r;
        *(float4*)(qkv + ((size_t)n * 256 + o) * 128 + l0) =
            make_float4(acc[r][0], acc[r][1], acc[r][2], acc[r][3]);
        float s  = acc[r][0] + acc[r][1] + acc[r][2] + acc[r][3];
        float sq = acc[r][0]*acc[r][0] + acc[r][1]*acc[r][1] + acc[r][2]*acc[r][2] + acc[r][3]*acc[r][3];
#pragma unroll
        for (int m = 1; m < 32; m <<= 1) {
            s  += __shfl_xor(s, m);
            sq += __shfl_xor(sq, m);
        }
        if (tl == 0) {
            atomicAdd(&stats[o], s);
            atomicAdd(&stats[256 + o], sq);
        }
    }
}

__global__ void k3_coef_qkv(const float* __restrict__ stats,
                            const float* __restrict__ gamma, const float* __restrict__ beta,
                            float* __restrict__ coef)
{
    int o = threadIdx.x;
    const float cnt = 16384.f;
    float mean = stats[o] / cnt;
    float var  = stats[256 + o] / cnt - mean * mean;
    float a = gamma[o] * rsqrtf(var + EPS);
    coef[o] = a;
    coef[256 + o] = beta[o] - a * mean;
}

// ============================================================
// K4 v3 (pass 1): unchanged (512 thr, MFMA).
// ============================================================
__global__ __launch_bounds__(512, 4) void k4_pass1(
    const float* __restrict__ qkv, const float* __restrict__ rel,
    const float* __restrict__ cq, u16* __restrict__ qk,
    float* __restrict__ stats)
{
    __shared__ u16 QEb[128 * 136];
    __shared__ u16 KEb[128 * 136];
    __shared__ float red[8 * 6];
    const int tid = threadIdx.x;
    const int n = blockIdx.x >> 4, g = blockIdx.x & 15;

    const int pt = tid & 31, pi = tid >> 5;
    const int t0 = pt * 4, i0 = pi * 8;
    const int d0 = t0 - i0 + 120;

    float qes = 0.f, qesq = 0.f, kes = 0.f, kesq = 0.f;

#pragma unroll
    for (int mat = 0; mat < 2; ++mat) {
        float qv[4][4];
#pragma unroll
        for (int c = 0; c < 4; ++c) {
            int o = g * 16 + mat * 4 + c;
            float a = cq[o], bb = cq[256 + o];
            float4 x0 = *(const float4*)(qkv + ((size_t)n * 256 + o) * 128 + t0);
            qv[c][0] = fmaf(a, x0.x, bb); qv[c][1] = fmaf(a, x0.y, bb);
            qv[c][2] = fmaf(a, x0.z, bb); qv[c][3] = fmaf(a, x0.w, bb);
        }
        float rr[4][12];
#pragma unroll
        for (int c = 0; c < 4; ++c) {
            const float* p = rel + (mat * 4 + c) * 255 + d0;
#pragma unroll
            for (int j = 0; j < 3; ++j) {
                float4 v = *(const float4*)(p + j * 4);
                rr[c][j*4+0] = v.x; rr[c][j*4+1] = v.y;
                rr[c][j*4+2] = v.z; rr[c][j*4+3] = v.w;
            }
        }
        u16* MB = mat ? KEb : QEb;
        float s = 0.f, sq = 0.f;
#pragma unroll
        for (int ii = 0; ii < 8; ++ii) {
            float vv[4];
#pragma unroll
            for (int tt = 0; tt < 4; ++tt) {
                int dl = tt - ii + 7;
                float v = qv[0][tt] * rr[0][dl] + qv[1][tt] * rr[1][dl]
                        + qv[2][tt] * rr[2][dl] + qv[3][tt] * rr[3][dl];
                vv[tt] = v;
                s += v; sq = fmaf(v, v, sq);
            }
            *(uint2*)(MB + (i0 + ii) * 136 + t0) =
                make_uint2(pack2(vv[0], vv[1]), pack2(vv[2], vv[3]));
        }
        if (mat == 0) { qes = s; qesq = sq; } else { kes = s; kesq = sq; }
    }
    __syncthreads();

    const int lane = tid & 63, wv = tid >> 6;
    const int fm = lane & 15, fq = lane >> 4;

    f32x4 acc[8];
#pragma unroll
    for (int tj = 0; tj < 8; ++tj) acc[tj] = (f32x4){0.f, 0.f, 0.f, 0.f};

#pragma unroll
    for (int kb = 0; kb < 4; ++kb) {
        const int ko = kb * 32 + fq * 8;
        bf16x8 a0 = *(const bf16x8*)(QEb + (wv * 16 + fm) * 136 + ko);
#pragma unroll
        for (int tj = 0; tj < 8; ++tj) {
            bf16x8 bfr = *(const bf16x8*)(KEb + (tj * 16 + fm) * 136 + ko);
            acc[tj] = __builtin_amdgcn_mfma_f32_16x16x32_bf16(a0, bfr, acc[tj], 0, 0, 0);
        }
    }

    float qks = 0.f, qksq = 0.f;
#pragma unroll
    for (int tj = 0; tj < 8; ++tj) {
#pragma unroll
        for (int r = 0; r < 4; ++r) {
            float v = acc[tj][r];
            qks += v; qksq = fmaf(v, v, qksq);
            QEb[(wv * 16 + fq * 4 + r) * 136 + tj * 16 + fm] = f2bf(v);
        }
    }

#pragma unroll
    for (int m = 1; m < 64; m <<= 1) {
        qes += __shfl_xor(qes, m);  qesq += __shfl_xor(qesq, m);
        kes += __shfl_xor(kes, m);  kesq += __shfl_xor(kesq, m);
        qks += __shfl_xor(qks, m);  qksq += __shfl_xor(qksq, m);
    }
    if (lane == 0) {
        red[wv * 6 + 0] = qes; red[wv * 6 + 1] = qesq;
        red[wv * 6 + 2] = kes; red[wv * 6 + 3] = kesq;
        red[wv * 6 + 4] = qks; red[wv * 6 + 5] = qksq;
    }
    __syncthreads();

    u16* qkg = qk + (size_t)(n * 16 + g) * 16384;
#pragma unroll
    for (int k = 0; k < 4; ++k) {
        int f = tid + k * 512;
        int row = f >> 4, c8 = f & 15;
        uint4 v = *(const uint4*)(QEb + row * 136 + c8 * 8);
        *(uint4*)(qkg + row * 128 + c8 * 8) = v;
    }

    if (tid < 6) {
        float tot = 0.f;
#pragma unroll
        for (int w = 0; w < 8; ++w) tot += red[w * 6 + tid];
        int off = (tid & 1) ? 560 : 512;
        int ch = (tid < 2) ? (16 + g) : (tid < 4) ? (32 + g) : g;
        atomicAdd(&stats[off + ch], tot);
    }
}

__global__ void k5_coef_sim(const float* __restrict__ stats,
                            const float* __restrict__ gamma, const float* __restrict__ beta,
                            float* __restrict__ coef)
{
    int ch = threadIdx.x;
    if (ch < 48) {
        const float cnt = 2097152.f;
        float mean = stats[512 + ch] / cnt;
        float var  = stats[560 + ch] / cnt - mean * mean;
        float a = gamma[ch] * rsqrtf(var + EPS);
        coef[ch] = a;
        coef[48 + ch] = beta[ch] - a * mean;
    }
}

// ============================================================
// K6 v8 (pass 2): R9's proven 128-thread row-per-lane kernel with
// EXPLICIT 4-DEEP LOAD BATCHING. R9's 490 cyc/iter = 3 dependent
// ds_read_b128 waits (~130 cyc each, compiler at self-chosen 52 VGPR
// couldn't hold loads in flight) + ~100 cyc VALU. v8 issues 12
// independent named b128 loads per 4-iteration group, then computes —
// one wait covers 12 loads. aqe/ake folded into q/k regs (once/row).
// 256-thread k6 is ABANDONED: 4/4 builds spilled (R6,R7,R8,R10),
// 2/2 128-thread builds didn't (R5,R9).
// ============================================================
#define K6_STEP(rb, rv, vv, jl)                                              \
    {                                                                        \
        float qe = q0 * bf2f((u16)rb[0]) + q1 * bf2f((u16)rb[1])             \
                 + q2 * bf2f((u16)rb[2]) + q3 * bf2f((u16)rb[3]);            \
        float ke = k0 * bf2f((u16)rb[4]) + k1 * bf2f((u16)rb[5])             \
                 + k2 * bf2f((u16)rb[6]) + k3 * bf2f((u16)rb[7]);            \
        float s = fmaf(aqk, bf2f(qh.hh[jl]), qe + ke + bsum);                \
        float e = __expf(s);                                                 \
        l += e;                                                              \
        _Pragma("unroll")                                                    \
        for (int c = 0; c < 8; ++c) {                                        \
            am[c]  = fmaf(e, bf2f((u16)vv[c]), am[c]);                       \
            ame[c] = fmaf(e, bf2f((u16)rv[c]), ame[c]);                      \
        }                                                                    \
    }

__global__ __launch_bounds__(128, 4) void k6_pass2(
    const float* __restrict__ qkv, const float* __restrict__ rel,
    const float* __restrict__ cq, const float* __restrict__ cs,
    const u16* __restrict__ qk,
    float* __restrict__ outraw, float* __restrict__ ostats)
{
    __shared__ u16 relb[256 * 24];     // [d][ch], d<255
    __shared__ u16 vb[128 * 8];        // [j][c]
    __shared__ float qn_s[8 * 128];    // q rows 0..3, k rows 4..7 (normalized)
    const int tid = threadIdx.x;       // 0..127 = row i
    const int n = blockIdx.x >> 4, g = blockIdx.x & 15;

    // stage relb: 16 ch x 255 d
#pragma unroll
    for (int k = 0; k < 32; ++k) {
        int f = tid + k * 128;          // < 4096
        int c = f >> 8, d = f & 255;
        if (d < 255) relb[d * 24 + c] = f2bf(rel[c * 255 + d]);
    }
    // stage qn_s (q,k normalized fp32)
#pragma unroll
    for (int k = 0; k < 8; ++k) {
        int f = tid + k * 128;          // < 1024
        int c = f >> 7, t = f & 127;
        int o = g * 16 + c;
        qn_s[f] = fmaf(cq[o], qkv[((size_t)n * 256 + o) * 128 + t], cq[256 + o]);
    }
    // stage vb (v normalized bf16)
#pragma unroll
    for (int k = 0; k < 8; ++k) {
        int f = tid + k * 128;          // < 1024
        int c = f >> 7, j = f & 127;
        int o = g * 16 + 8 + c;
        float v = fmaf(cq[o], qkv[((size_t)n * 256 + o) * 128 + j], cq[256 + o]);
        vb[j * 8 + c] = f2bf(v);
    }
    __syncthreads();

    const float aqk = cs[g], aqe = cs[16 + g], ake = cs[32 + g];
    const float bsum = cs[48 + g] + cs[64 + g] + cs[80 + g];
    const int i = tid;

    // fold BN-sim scales into the per-row q/k registers (once per row)
    float q0 = aqe * qn_s[i],       q1 = aqe * qn_s[128 + i];
    float q2 = aqe * qn_s[256 + i], q3 = aqe * qn_s[384 + i];
    float k0 = ake * qn_s[512 + i], k1 = ake * qn_s[640 + i];
    float k2 = ake * qn_s[768 + i], k3 = ake * qn_s[896 + i];

    const u16* qkrow = qk + (size_t)(n * 16 + g) * 16384 + i * 128;

    float l = 0.f;
    float am[8], ame[8];
#pragma unroll
    for (int c = 0; c < 8; ++c) { am[c] = 0.f; ame[c] = 0.f; }

#pragma unroll
    for (int jc = 0; jc < 8; ++jc) {
        // qk chunk (16 bf16, per-lane contiguous, 16B aligned)
        union { uint4 v[2]; u16 hh[16]; } qh;
        qh.v[0] = *(const uint4*)(qkrow + jc * 16);
        qh.v[1] = *(const uint4*)(qkrow + jc * 16 + 8);

        const int dbase = i + 127 - jc * 16;
#pragma unroll
        for (int js = 0; js < 4; ++js) {
            const int dd = dbase - js * 4;
            const int jj = jc * 16 + js * 4;
            // 12 independent LDS loads, issued before any use
            bf16x8 rb0 = *(const bf16x8*)(relb + (dd    ) * 24);
            bf16x8 rb1 = *(const bf16x8*)(relb + (dd - 1) * 24);
            bf16x8 rb2 = *(const bf16x8*)(relb + (dd - 2) * 24);
            bf16x8 rb3 = *(const bf16x8*)(relb + (dd - 3) * 24);
            bf16x8 rv0 = *(const bf16x8*)(relb + (dd    ) * 24 + 8);
            bf16x8 rv1 = *(const bf16x8*)(relb + (dd - 1) * 24 + 8);
            bf16x8 rv2 = *(const bf16x8*)(relb + (dd - 2) * 24 + 8);
            bf16x8 rv3 = *(const bf16x8*)(relb + (dd - 3) * 24 + 8);
            bf16x8 vv0 = *(const bf16x8*)(vb + (jj + 0) * 8);
            bf16x8 vv1 = *(const bf16x8*)(vb + (jj + 1) * 8);
            bf16x8 vv2 = *(const bf16x8*)(vb + (jj + 2) * 8);
            bf16x8 vv3 = *(const bf16x8*)(vb + (jj + 3) * 8);

            K6_STEP(rb0, rv0, vv0, js * 4 + 0);
            K6_STEP(rb1, rv1, vv1, js * 4 + 1);
            K6_STEP(rb2, rv2, vv2, js * 4 + 2);
            K6_STEP(rb3, rv3, vv3, js * 4 + 3);
        }
    }

    // epilogue: normalize, write out, BN stats (R9 shape, unchanged)
    float inv = 1.f / l;
    float o16[16];
#pragma unroll
    for (int c = 0; c < 8; ++c) { o16[2 * c] = am[c] * inv; o16[2 * c + 1] = ame[c] * inv; }

    float* orow = outraw + ((size_t)n * 256 + g * 16) * 128 + i;
#pragma unroll
    for (int c16 = 0; c16 < 16; ++c16) orow[c16 * 128] = o16[c16];

    const int lane = tid & 63;
#pragma unroll
    for (int c16 = 0; c16 < 16; ++c16) {
        float sv = o16[c16], sq = o16[c16] * o16[c16];
#pragma unroll
        for (int mm = 1; mm < 64; mm <<= 1) { sv += __shfl_xor(sv, mm); sq += __shfl_xor(sq, mm); }
        if (lane == 0) {
            atomicAdd(&ostats[g * 16 + c16], sv);
            atomicAdd(&ostats[256 + g * 16 + c16], sq);
        }
    }
}

__global__ void k7_coef_out(const float* __restrict__ stats,
                            const float* __restrict__ gamma, const float* __restrict__ beta,
                            float* __restrict__ coef)
{
    int o = threadIdx.x;
    const float cnt = 16384.f;
    float mean = stats[608 + o] / cnt;
    float var  = stats[864 + o] / cnt - mean * mean;
    float a = gamma[o] * rsqrtf(var + EPS);
    coef[o] = a;
    coef[256 + o] = beta[o] - a * mean;
}

__global__ __launch_bounds__(256) void k8_final(
    const float* __restrict__ outraw, const float* __restrict__ co,
    float* __restrict__ out)
{
    int idx = blockIdx.x * 256 + threadIdx.x;
    int w  = idx & 127;
    int h  = (idx >> 7) & 63;
    int oc = (idx >> 13) & 127;
    int b  = idx >> 20;
    int n  = b * 64 + h;
    int o0 = oc * 2;
    float x0 = outraw[((size_t)n * 256 + o0) * 128 + w];
    float x1 = outraw[((size_t)n * 256 + o0 + 1) * 128 + w];
    out[idx] = (co[o0] * x0 + co[256 + o0]) + (co[o0 + 1] * x1 + co[256 + o0 + 1]);
}

// ============================================================
// Workspace layout (floats): unchanged from round 0.
// ============================================================
extern "C" void kernel_launch(void* const* d_in, const int* in_sizes, int n_in,
                              void* d_out, int out_size, void* d_ws, size_t ws_size,
                              hipStream_t stream)
{
    const float* x   = (const float*)d_in[0];
    const float* Wq  = (const float*)d_in[1];
    const float* gq  = (const float*)d_in[2];
    const float* bq  = (const float*)d_in[3];
    const float* rel = (const float*)d_in[4];
    const float* gs  = (const float*)d_in[5];
    const float* bs  = (const float*)d_in[6];
    const float* go  = (const float*)d_in[7];
    const float* bo  = (const float*)d_in[8];

    float* ws     = (float*)d_ws;
    float* qkv    = ws;
    float* outraw = ws + 4194304;
    u16*   qk     = (u16*)(ws + 8388608);
    float* stats  = ws + 25165824;
    float* cq     = stats + 1120;
    float* cs     = stats + 1632;
    float* co     = stats + 1728;

    (void)hipMemsetAsync(stats, 0, 1120 * sizeof(float), stream);

    k1_gemm_qkv<<<dim3(4, 128), 256, 0, stream>>>(x, Wq, qkv, stats);
    k3_coef_qkv<<<1, 256, 0, stream>>>(stats, gq, bq, cq);
    k4_pass1<<<2048, 512, 0, stream>>>(qkv, rel, cq, qk, stats);
    k5_coef_sim<<<1, 64, 0, stream>>>(stats, gs, bs, cs);
    k6_pass2<<<2048, 128, 0, stream>>>(qkv, rel, cq, cs, qk, outraw, stats + 608);
    k7_coef_out<<<1, 256, 0, stream>>>(stats, go, bo, co);
    k8_final<<<8192, 256, 0, stream>>>(outraw, co, (float*)d_out);
}